// Round 9
// baseline (122.654 us; speedup 1.0000x reference)
//
#include <hip/hip_runtime.h>
#include <math.h>

// B=4, N=128, H=W=32, C=64.  out[b][j][n] = sigmoid(wl[j,:] . mean_hw MLP(...) + bl[j])
//
// MFMA: layers 2..5 are 64x64 GEMMs over pixel columns (16x16x32_bf16,
// M=64ch x N=16px per MFMA); layer 1 (7->64) K=32 zero-padded.
//
// R9: WEIGHTS PERSISTENT IN REGISTERS. R8 post-mortem: kernel ~37us, DS-pipe
// ~54% busy, half of loop DS reads are the per-layer af weight re-reads.
// R5 mystery resolved: __launch_bounds__ sets only a MINIMUM occupancy —
// allocator still targeted 4 waves/EU (128 VGPR) and spilled. Fix:
// __attribute__((amdgpu_waves_per_eu(2,2))) forces the 256-VGPR budget
// (gfx950 unified VGPR/AGPR file; MFMA A-operands can live in AGPRs).
// wf[4][4][2] frags (128 regs) + a1 (16) loaded once from the LDS staging
// area; the t-loop body then has NO weight loads: bf act reads + MFMA only.
// DS model: 128 b128 + 256 b64 per wave per 4t -> ~27K cyc/CU ~ 11us floor.
// Tripwires: VGPR_Count ~240-256 & WRITE_SIZE ~48B (else attr failed/spill).
// Act transform C->B via wave-private LDS (no barriers in main loop):
//   C: col=lane&15, row=(lane>>4)*4+reg   [m89-verified]
//   A/B: n=lane&15, k=(lane>>4)*8+j        [m120-verified]

typedef float  f32x4  __attribute__((ext_vector_type(4)));
typedef f32x4  f32x4a __attribute__((may_alias));
typedef __bf16 bf16x8 __attribute__((ext_vector_type(8)));
typedef bf16x8 bf16x8a __attribute__((may_alias));
typedef __bf16 bf16x4 __attribute__((ext_vector_type(4)));
typedef bf16x4 bf16x4a __attribute__((may_alias));
typedef float  floata __attribute__((may_alias));

#define MFMA16(a, b, c) __builtin_amdgcn_mfma_f32_16x16x32_bf16((a), (b), (c), 0, 0, 0)

// LDS halfword offsets
#define WL_H    0            // 36 frag-groups x 512 halfwords (36864 B)
#define ACT_H   18432        // 4 waves x 4096 halfwords (32768 B)

__global__ __launch_bounds__(256)
__attribute__((amdgpu_waves_per_eu(2, 2)))
void mlp_mfma_kernel(
    const float* __restrict__ image,   // [4,3,32,32]
    const float* __restrict__ coords,  // [4,128,2]
    const float* __restrict__ w1, const float* __restrict__ b1,   // [64,7],[64]
    const float* __restrict__ w2, const float* __restrict__ b2,   // [64,64],[64]
    const float* __restrict__ w3, const float* __restrict__ b3,
    const float* __restrict__ w4, const float* __restrict__ b4,
    const float* __restrict__ w5, const float* __restrict__ b5,
    const float* __restrict__ wl, const float* __restrict__ bl,   // [3,64],[3]
    float* __restrict__ out)           // [4,3,128]
{
    __shared__ __align__(16) __bf16 LDSH[18432 + 16384];  // weights + acts
    __shared__ __align__(16) float  BL[320];              // biases [5][64]

    const int tid  = threadIdx.x;
    const int wave = tid >> 6;
    const int lane = tid & 63;
    const int c15  = lane & 15;
    const int q    = lane >> 4;
    const int bn   = blockIdx.x;
    const int b    = bn >> 7;

    const float qm = (q == 0) ? 1.0f : 0.0f;   // layer-1 K=32 zero-pad mask

    const float* Ws[4] = {w2, w3, w4, w5};

    // ---- stage weight A-frags into LDS, lane-major: frag id*512h + lane*8h
    //   id = l*8 + mt*2 + ks  (l=0..3 -> w2..w5), id = 32+mt -> w1
    #pragma unroll 1
    for (int i = 0; i < 9; ++i) {
        const int id = wave + i * 4;           // 4 waves cover 0..35
        __bf16* dst = &LDSH[WL_H + id * 512 + lane * 8];
        if (id < 32) {
            const int l  = id >> 3;
            const int mt = (id >> 1) & 3;
            const int ks = id & 1;
            const float* src = Ws[l] + (mt * 16 + c15) * 64 + ks * 32 + q * 8;
            f32x4 lo = *(const f32x4a*)src;
            f32x4 hi = *(const f32x4a*)(src + 4);
            bf16x8 f;
            f[0] = (__bf16)lo[0]; f[1] = (__bf16)lo[1];
            f[2] = (__bf16)lo[2]; f[3] = (__bf16)lo[3];
            f[4] = (__bf16)hi[0]; f[5] = (__bf16)hi[1];
            f[6] = (__bf16)hi[2]; f[7] = (__bf16)hi[3];
            *(bf16x8a*)dst = f;
        } else {
            const int mt = id - 32;
            bf16x8 f;
            #pragma unroll
            for (int j = 0; j < 7; ++j)
                f[j] = (__bf16)(qm * w1[(mt * 16 + c15) * 7 + j]);
            f[7] = (__bf16)0.0f;
            *(bf16x8a*)dst = f;
        }
    }
    if (tid < 64) {
        BL[tid]       = b1[tid];
        BL[64 + tid]  = b2[tid];
        BL[128 + tid] = b3[tid];
        BL[192 + tid] = b4[tid];
        BL[256 + tid] = b5[tid];
    }
    __syncthreads();

    // ---- load ALL weight frags into registers, once (wf: 128 VGPR/AGPR)
    bf16x8 wf[4][4][2];
    #pragma unroll
    for (int l = 0; l < 4; ++l)
        #pragma unroll
        for (int mt = 0; mt < 4; ++mt)
            #pragma unroll
            for (int ks = 0; ks < 2; ++ks)
                wf[l][mt][ks] = *(const bf16x8a*)
                    &LDSH[WL_H + (l * 8 + mt * 2 + ks) * 512 + lane * 8];
    bf16x8 a1[4];
    #pragma unroll
    for (int mt = 0; mt < 4; ++mt)
        a1[mt] = *(const bf16x8a*)&LDSH[WL_H + (32 + mt) * 512 + lane * 8];

    const float cx = coords[2 * bn + 0];
    const float cy = coords[2 * bn + 1];
    const float* img = image + b * 3072;

    __bf16* Xw = &LDSH[ACT_H + wave * 4096];   // 2 tiles x 2048 halfwords
    const int lane_woff = c15 * 8 + (q >> 1) * 128 + (q & 1) * 4;

    f32x4 pool[4];
    #pragma unroll
    for (int mt = 0; mt < 4; ++mt) pool[mt] = (f32x4){0.f, 0.f, 0.f, 0.f};

    // leaky + cvt + C->B transform of one 32-px tile into its act region
    auto store_tile = [&](f32x4 (&acc)[4][2], int g) {
        #pragma unroll
        for (int mt = 0; mt < 4; ++mt)
            #pragma unroll
            for (int ntl = 0; ntl < 2; ++ntl) {
                f32x4 a = acc[mt][ntl];
                bf16x4 p;
                #pragma unroll
                for (int r = 0; r < 4; ++r) {
                    float v = fmaxf(a[r], 0.1f * a[r]);
                    p[r] = (__bf16)v;
                }
                const int off = g * 2048 + (ntl * 2 + (mt >> 1)) * 512
                              + (mt & 1) * 256 + lane_woff;
                *(bf16x4a*)&Xw[off] = p;
            }
    };

    #pragma unroll 1
    for (int t = 0; t < 4; ++t) {           // 4 passes x 64 px (2 tiles)
        // ======== layer 1 ========
        {
            f32x4 bv[4];
            #pragma unroll
            for (int mt = 0; mt < 4; ++mt)
                bv[mt] = *(const f32x4a*)&BL[mt * 16 + 4 * q];

            #pragma unroll
            for (int g = 0; g < 2; ++g) {
                bf16x8 bft[2];
                #pragma unroll
                for (int ntl = 0; ntl < 2; ++ntl) {
                    const int hw = wave * 256 + t * 64 + g * 32 + ntl * 16 + c15;
                    const float i0 = img[hw];
                    const float i1 = img[1024 + hw];
                    const float i2 = img[2048 + hw];
                    bf16x8 f;
                    f[0] = (__bf16)(qm * i0);
                    f[1] = (__bf16)(qm * i1);
                    f[2] = (__bf16)(qm * i2);
                    f[3] = (__bf16)(qm * (float)(hw >> 5) * (1.0f / 31.0f));
                    f[4] = (__bf16)(qm * (float)(hw & 31) * (1.0f / 31.0f));
                    f[5] = (__bf16)(qm * cx);
                    f[6] = (__bf16)(qm * cy);
                    f[7] = (__bf16)0.0f;
                    bft[ntl] = f;
                }
                f32x4 acc[4][2];
                #pragma unroll
                for (int mt = 0; mt < 4; ++mt) {
                    acc[mt][0] = bv[mt]; acc[mt][1] = bv[mt];
                }
                #pragma unroll
                for (int mt = 0; mt < 4; ++mt)
                    #pragma unroll
                    for (int ntl = 0; ntl < 2; ++ntl)
                        acc[mt][ntl] = MFMA16(a1[mt], bft[ntl], acc[mt][ntl]);
                store_tile(acc, g);
            }
        }

        // ======== layers 2..5 — unrolled; weights already in registers ====
        #pragma unroll
        for (int l = 0; l < 4; ++l) {
            f32x4 bv[4];
            #pragma unroll
            for (int mt = 0; mt < 4; ++mt)
                bv[mt] = *(const f32x4a*)&BL[(l + 1) * 64 + mt * 16 + 4 * q];

            #pragma unroll
            for (int g = 0; g < 2; ++g) {
                bf16x8 bf[2][2];
                #pragma unroll
                for (int ntl = 0; ntl < 2; ++ntl)
                    #pragma unroll
                    for (int ks = 0; ks < 2; ++ks)
                        bf[ntl][ks] = *(const bf16x8a*)
                            &Xw[g * 2048 + ((ntl * 2 + ks) * 64 + lane) * 8];
                f32x4 acc[4][2];
                #pragma unroll
                for (int mt = 0; mt < 4; ++mt) {
                    acc[mt][0] = bv[mt]; acc[mt][1] = bv[mt];
                }
                #pragma unroll
                for (int mt = 0; mt < 4; ++mt)
                    #pragma unroll
                    for (int ntl = 0; ntl < 2; ++ntl)
                        #pragma unroll
                        for (int ks = 0; ks < 2; ++ks)
                            acc[mt][ntl] = MFMA16(wf[l][mt][ks], bf[ntl][ks], acc[mt][ntl]);
                if (l < 3) {
                    store_tile(acc, g);
                } else {
                    #pragma unroll
                    for (int mt = 0; mt < 4; ++mt)
                        #pragma unroll
                        for (int ntl = 0; ntl < 2; ++ntl) {
                            f32x4 a = acc[mt][ntl];
                            #pragma unroll
                            for (int r = 0; r < 4; ++r)
                                pool[mt][r] += fmaxf(a[r], 0.1f * a[r]);
                        }
                }
            }
        }
    }

    // ---- pool partials -> float view of this wave's act region: [ch][col16]
    floata* Xf = (floata*)Xw;
    #pragma unroll
    for (int mt = 0; mt < 4; ++mt)
        #pragma unroll
        for (int r = 0; r < 4; ++r)
            Xf[(mt * 16 + 4 * q + r) * 16 + c15] = pool[mt][r];

    __syncthreads();

    // ---- block reduce (4 waves x 16 cols) + head + sigmoid
    if (tid < 64) {
        const int c = tid;
        float s = 0.0f;
        #pragma unroll
        for (int w = 0; w < 4; ++w) {
            const floata* P = (const floata*)&LDSH[ACT_H + w * 4096];
            #pragma unroll
            for (int c4 = 0; c4 < 4; ++c4) {
                f32x4 v = *(const f32x4a*)&P[c * 16 + c4 * 4];
                s += v[0] + v[1] + v[2] + v[3];
            }
        }
        const float p = s * (1.0f / 1024.0f);
        float s0 = wl[c] * p;
        float s1 = wl[64 + c] * p;
        float s2 = wl[128 + c] * p;
        #pragma unroll
        for (int off = 32; off > 0; off >>= 1) {
            s0 += __shfl_down(s0, off, 64);
            s1 += __shfl_down(s1, off, 64);
            s2 += __shfl_down(s2, off, 64);
        }
        if (c == 0) {
            const int n = bn & 127;
            out[(b * 3 + 0) * 128 + n] = 1.0f / (1.0f + expf(-(bl[0] + s0)));
            out[(b * 3 + 1) * 128 + n] = 1.0f / (1.0f + expf(-(bl[1] + s1)));
            out[(b * 3 + 2) * 128 + n] = 1.0f / (1.0f + expf(-(bl[2] + s2)));
        }
    }
}

extern "C" void kernel_launch(void* const* d_in, const int* in_sizes, int n_in,
                              void* d_out, int out_size, void* d_ws, size_t ws_size,
                              hipStream_t stream) {
    const float* image  = (const float*)d_in[0];
    const float* coords = (const float*)d_in[1];
    const float* w1 = (const float*)d_in[2];
    const float* b1 = (const float*)d_in[3];
    const float* w2 = (const float*)d_in[4];
    const float* b2 = (const float*)d_in[5];
    const float* w3 = (const float*)d_in[6];
    const float* b3 = (const float*)d_in[7];
    const float* w4 = (const float*)d_in[8];
    const float* b4 = (const float*)d_in[9];
    const float* w5 = (const float*)d_in[10];
    const float* b5 = (const float*)d_in[11];
    const float* wl = (const float*)d_in[12];
    const float* bl = (const float*)d_in[13];
    float* out = (float*)d_out;

    mlp_mfma_kernel<<<dim3(512), dim3(256), 0, stream>>>(
        image, coords, w1, b1, w2, b2, w3, b3, w4, b4, w5, b5, wl, bl, out);
}

// Round 10
// 113.132 us; speedup vs baseline: 1.0842x; 1.0842x over previous
//
#include <hip/hip_runtime.h>
#include <math.h>

// B=4, N=128, H=W=32, C=64.  out[b][j][n] = sigmoid(wl[j,:] . mean_hw MLP(...) + bl[j])
//
// MFMA: layers 2..5 are 64x64 GEMMs over pixel columns (16x16x32_bf16,
// M=64ch x N=16px per MFMA); layer 1 (7->64) K=32 zero-padded.
// Weights staged once per block into LDS, lane-major -> ds_read_b128.
//
// R10: OCCUPANCY via 8-wave blocks. R9 post-mortem: amdgpu_waves_per_eu(2,2)
// did NOT raise the 128-VGPR wall (VGPR=128, spill back, 51us) — weights
// cannot be register-resident on this toolchain; R8 (~37us, 2 waves/SIMD,
// no pipe >50%) is the base. R4's 8-wave failure was weight-scratch L1
// contention — gone since weights moved to LDS (R6). So: 512 blocks x 512
// thr (8 waves), G=1 (wave = 4 passes x 32px tile). LDS 71KB -> 2 blocks/CU
// -> 16 waves/CU = 4 waves/SIMD (2x R8). DS floor rises to ~13.7us (G=1
// halves af amortization) but DS was only ~46% busy — now it saturates
// instead of idling. launch_bounds(512,2): R4-verified to give the 128 cap.
// Tripwire: WRITE_SIZE must stay ~48B (no spill).
// Act transform C->B via wave-private LDS (no barriers in main loop):
//   C: col=lane&15, row=(lane>>4)*4+reg   [m89-verified]
//   A/B: n=lane&15, k=(lane>>4)*8+j        [m120-verified]

typedef float  f32x4  __attribute__((ext_vector_type(4)));
typedef f32x4  f32x4a __attribute__((may_alias));
typedef __bf16 bf16x8 __attribute__((ext_vector_type(8)));
typedef bf16x8 bf16x8a __attribute__((may_alias));
typedef __bf16 bf16x4 __attribute__((ext_vector_type(4)));
typedef bf16x4 bf16x4a __attribute__((may_alias));
typedef float  floata __attribute__((may_alias));

#define MFMA16(a, b, c) __builtin_amdgcn_mfma_f32_16x16x32_bf16((a), (b), (c), 0, 0, 0)

// LDS halfword offsets
#define WL_H    0            // 36 frag-groups x 512 halfwords (36864 B)
#define ACT_H   18432        // 8 waves x 2048 halfwords (32768 B)

__global__ __launch_bounds__(512, 2) void mlp_mfma_kernel(
    const float* __restrict__ image,   // [4,3,32,32]
    const float* __restrict__ coords,  // [4,128,2]
    const float* __restrict__ w1, const float* __restrict__ b1,   // [64,7],[64]
    const float* __restrict__ w2, const float* __restrict__ b2,   // [64,64],[64]
    const float* __restrict__ w3, const float* __restrict__ b3,
    const float* __restrict__ w4, const float* __restrict__ b4,
    const float* __restrict__ w5, const float* __restrict__ b5,
    const float* __restrict__ wl, const float* __restrict__ bl,   // [3,64],[3]
    float* __restrict__ out)           // [4,3,128]
{
    __shared__ __align__(16) __bf16 LDSH[18432 + 16384];  // weights + acts
    __shared__ __align__(16) float  BL[320];              // biases [5][64]

    const int tid  = threadIdx.x;
    const int wave = tid >> 6;      // 0..7
    const int lane = tid & 63;
    const int c15  = lane & 15;
    const int q    = lane >> 4;
    const int bn   = blockIdx.x;
    const int b    = bn >> 7;

    const float qm = (q == 0) ? 1.0f : 0.0f;   // layer-1 K=32 zero-pad mask

    const float* Ws[4] = {w2, w3, w4, w5};

    // ---- stage weight A-frags into LDS, lane-major: frag id*512h + lane*8h
    //   id = l*8 + mt*2 + ks  (l=0..3 -> w2..w5), id = 32+mt -> w1
    #pragma unroll 1
    for (int i = 0; i < 5; ++i) {
        const int id = wave + i * 8;           // 8 waves cover 0..39
        if (id < 36) {
            __bf16* dst = &LDSH[WL_H + id * 512 + lane * 8];
            if (id < 32) {
                const int l  = id >> 3;
                const int mt = (id >> 1) & 3;
                const int ks = id & 1;
                const float* src = Ws[l] + (mt * 16 + c15) * 64 + ks * 32 + q * 8;
                f32x4 lo = *(const f32x4a*)src;
                f32x4 hi = *(const f32x4a*)(src + 4);
                bf16x8 f;
                f[0] = (__bf16)lo[0]; f[1] = (__bf16)lo[1];
                f[2] = (__bf16)lo[2]; f[3] = (__bf16)lo[3];
                f[4] = (__bf16)hi[0]; f[5] = (__bf16)hi[1];
                f[6] = (__bf16)hi[2]; f[7] = (__bf16)hi[3];
                *(bf16x8a*)dst = f;
            } else {
                const int mt = id - 32;
                bf16x8 f;
                #pragma unroll
                for (int j = 0; j < 7; ++j)
                    f[j] = (__bf16)(qm * w1[(mt * 16 + c15) * 7 + j]);
                f[7] = (__bf16)0.0f;
                *(bf16x8a*)dst = f;
            }
        }
    }
    if (tid < 64) {
        BL[tid]       = b1[tid];
        BL[64 + tid]  = b2[tid];
        BL[128 + tid] = b3[tid];
        BL[192 + tid] = b4[tid];
        BL[256 + tid] = b5[tid];
    }
    __syncthreads();

    // ---- hoist layer-1 A-frags into registers (16 regs, loop-invariant)
    bf16x8 a1[4];
    #pragma unroll
    for (int mt = 0; mt < 4; ++mt)
        a1[mt] = *(const bf16x8a*)&LDSH[WL_H + (32 + mt) * 512 + lane * 8];

    const float cx = coords[2 * bn + 0];
    const float cy = coords[2 * bn + 1];
    const float* img = image + b * 3072;

    __bf16* Xw = &LDSH[ACT_H + wave * 2048];   // one 32-px tile (4KB)
    const int lane_woff = c15 * 8 + (q >> 1) * 128 + (q & 1) * 4;

    f32x4 pool[4];
    #pragma unroll
    for (int mt = 0; mt < 4; ++mt) pool[mt] = (f32x4){0.f, 0.f, 0.f, 0.f};

    // leaky + cvt + C->B transform of the 32-px tile into this wave's region
    auto store_tile = [&](f32x4 (&acc)[4][2]) {
        #pragma unroll
        for (int mt = 0; mt < 4; ++mt)
            #pragma unroll
            for (int ntl = 0; ntl < 2; ++ntl) {
                f32x4 a = acc[mt][ntl];
                bf16x4 p;
                #pragma unroll
                for (int r = 0; r < 4; ++r) {
                    float v = fmaxf(a[r], 0.1f * a[r]);
                    p[r] = (__bf16)v;
                }
                const int off = (ntl * 2 + (mt >> 1)) * 512
                              + (mt & 1) * 256 + lane_woff;
                *(bf16x4a*)&Xw[off] = p;
            }
    };

    #pragma unroll 1
    for (int t = 0; t < 4; ++t) {           // 4 passes x 32 px
        // ======== layer 1 ========
        {
            f32x4 bv[4];
            #pragma unroll
            for (int mt = 0; mt < 4; ++mt)
                bv[mt] = *(const f32x4a*)&BL[mt * 16 + 4 * q];

            bf16x8 bft[2];
            #pragma unroll
            for (int ntl = 0; ntl < 2; ++ntl) {
                const int hw = wave * 128 + t * 32 + ntl * 16 + c15;
                const float i0 = img[hw];
                const float i1 = img[1024 + hw];
                const float i2 = img[2048 + hw];
                bf16x8 f;
                f[0] = (__bf16)(qm * i0);
                f[1] = (__bf16)(qm * i1);
                f[2] = (__bf16)(qm * i2);
                f[3] = (__bf16)(qm * (float)(hw >> 5) * (1.0f / 31.0f));
                f[4] = (__bf16)(qm * (float)(hw & 31) * (1.0f / 31.0f));
                f[5] = (__bf16)(qm * cx);
                f[6] = (__bf16)(qm * cy);
                f[7] = (__bf16)0.0f;
                bft[ntl] = f;
            }
            f32x4 acc[4][2];
            #pragma unroll
            for (int mt = 0; mt < 4; ++mt) {
                acc[mt][0] = bv[mt]; acc[mt][1] = bv[mt];
            }
            #pragma unroll
            for (int mt = 0; mt < 4; ++mt)
                #pragma unroll
                for (int ntl = 0; ntl < 2; ++ntl)
                    acc[mt][ntl] = MFMA16(a1[mt], bft[ntl], acc[mt][ntl]);
            store_tile(acc);
        }

        // ======== layers 2..5 — unrolled; weights from LDS ========
        #pragma unroll
        for (int l = 0; l < 4; ++l) {
            bf16x8 af[4][2];
            #pragma unroll
            for (int mt = 0; mt < 4; ++mt)
                #pragma unroll
                for (int ks = 0; ks < 2; ++ks)
                    af[mt][ks] = *(const bf16x8a*)
                        &LDSH[WL_H + (l * 8 + mt * 2 + ks) * 512 + lane * 8];
            f32x4 bv[4];
            #pragma unroll
            for (int mt = 0; mt < 4; ++mt)
                bv[mt] = *(const f32x4a*)&BL[(l + 1) * 64 + mt * 16 + 4 * q];

            bf16x8 bf[2][2];
            #pragma unroll
            for (int ntl = 0; ntl < 2; ++ntl)
                #pragma unroll
                for (int ks = 0; ks < 2; ++ks)
                    bf[ntl][ks] = *(const bf16x8a*)
                        &Xw[((ntl * 2 + ks) * 64 + lane) * 8];
            f32x4 acc[4][2];
            #pragma unroll
            for (int mt = 0; mt < 4; ++mt) {
                acc[mt][0] = bv[mt]; acc[mt][1] = bv[mt];
            }
            #pragma unroll
            for (int mt = 0; mt < 4; ++mt)
                #pragma unroll
                for (int ntl = 0; ntl < 2; ++ntl)
                    #pragma unroll
                    for (int ks = 0; ks < 2; ++ks)
                        acc[mt][ntl] = MFMA16(af[mt][ks], bf[ntl][ks], acc[mt][ntl]);
            if (l < 3) {
                store_tile(acc);
            } else {
                #pragma unroll
                for (int mt = 0; mt < 4; ++mt)
                    #pragma unroll
                    for (int ntl = 0; ntl < 2; ++ntl) {
                        f32x4 a = acc[mt][ntl];
                        #pragma unroll
                        for (int r = 0; r < 4; ++r)
                            pool[mt][r] += fmaxf(a[r], 0.1f * a[r]);
                    }
            }
        }
    }

    // ---- pool partials -> float view of this wave's act region: [ch][col16]
    floata* Xf = (floata*)Xw;
    #pragma unroll
    for (int mt = 0; mt < 4; ++mt)
        #pragma unroll
        for (int r = 0; r < 4; ++r)
            Xf[(mt * 16 + 4 * q + r) * 16 + c15] = pool[mt][r];

    __syncthreads();

    // ---- block reduce (8 waves x 16 cols) + head + sigmoid
    if (tid < 64) {
        const int c = tid;
        float s = 0.0f;
        #pragma unroll
        for (int w = 0; w < 8; ++w) {
            const floata* P = (const floata*)&LDSH[ACT_H + w * 2048];
            #pragma unroll
            for (int c4 = 0; c4 < 4; ++c4) {
                f32x4 v = *(const f32x4a*)&P[c * 16 + c4 * 4];
                s += v[0] + v[1] + v[2] + v[3];
            }
        }
        const float p = s * (1.0f / 1024.0f);
        float s0 = wl[c] * p;
        float s1 = wl[64 + c] * p;
        float s2 = wl[128 + c] * p;
        #pragma unroll
        for (int off = 32; off > 0; off >>= 1) {
            s0 += __shfl_down(s0, off, 64);
            s1 += __shfl_down(s1, off, 64);
            s2 += __shfl_down(s2, off, 64);
        }
        if (c == 0) {
            const int n = bn & 127;
            out[(b * 3 + 0) * 128 + n] = 1.0f / (1.0f + expf(-(bl[0] + s0)));
            out[(b * 3 + 1) * 128 + n] = 1.0f / (1.0f + expf(-(bl[1] + s1)));
            out[(b * 3 + 2) * 128 + n] = 1.0f / (1.0f + expf(-(bl[2] + s2)));
        }
    }
}

extern "C" void kernel_launch(void* const* d_in, const int* in_sizes, int n_in,
                              void* d_out, int out_size, void* d_ws, size_t ws_size,
                              hipStream_t stream) {
    const float* image  = (const float*)d_in[0];
    const float* coords = (const float*)d_in[1];
    const float* w1 = (const float*)d_in[2];
    const float* b1 = (const float*)d_in[3];
    const float* w2 = (const float*)d_in[4];
    const float* b2 = (const float*)d_in[5];
    const float* w3 = (const float*)d_in[6];
    const float* b3 = (const float*)d_in[7];
    const float* w4 = (const float*)d_in[8];
    const float* b4 = (const float*)d_in[9];
    const float* w5 = (const float*)d_in[10];
    const float* b5 = (const float*)d_in[11];
    const float* wl = (const float*)d_in[12];
    const float* bl = (const float*)d_in[13];
    float* out = (float*)d_out;

    mlp_mfma_kernel<<<dim3(512), dim3(512), 0, stream>>>(
        image, coords, w1, b1, w2, b2, w3, b3, w4, b4, w5, b5, wl, bl, out);
}